// Round 2
// baseline (149.707 us; speedup 1.0000x reference)
//
#include <hip/hip_runtime.h>

#define N_NODES 100000
#define N_EDGES 1600000
#define IN_DIM  128
#define HID_DIM 128
#define OUT_DIM 256

#define ECAP  1024    // cap on edges into node 0 (expected ~16)
#define SCAP  1056    // cap on |S| (>= ECAP+1)
#define ELCAP 8192    // cap on edges into S (expected ~280)

// ctrl: [0]=cnt edges into node0 (=indeg(0)), [1]=elist count, [2]=nS, [3]=nT, [4]=clamped elist count

// ---------------- init workspace ----------------
__global__ void k_init(int* __restrict__ flag, int* __restrict__ flag2,
                       int* __restrict__ ctrl, int* __restrict__ degS,
                       int* __restrict__ degT) {
    int i = blockIdx.x * blockDim.x + threadIdx.x;
    int stride = gridDim.x * blockDim.x;
    int4* f1 = (int4*)flag;
    int4* f2 = (int4*)flag2;
    const int n4 = N_NODES / 4;  // 25000
    int4 m1 = make_int4(-1, -1, -1, -1);
    for (int j = i; j < n4; j += stride) { f1[j] = m1; f2[j] = m1; }
    for (int j = i; j < SCAP; j += stride) degS[j] = 0;
    for (int j = i; j < ELCAP; j += stride) degT[j] = 0;
    if (i < 16) ctrl[i] = 0;
}

// ---------------- pass 1: find edges with dst==0 ----------------
__global__ void k_pass1(const int4* __restrict__ dst4, const int* __restrict__ src,
                        int* __restrict__ ctrl, int* __restrict__ e0src) {
    int i = blockIdx.x * blockDim.x + threadIdx.x;
    int stride = gridDim.x * blockDim.x;
    const int n4 = N_EDGES / 4;
    for (int q = i; q < n4; q += stride) {
        int4 d = dst4[q];
        if (d.x == 0) { int p = atomicAdd(&ctrl[0], 1); if (p < ECAP) e0src[p] = src[4*q+0]; }
        if (d.y == 0) { int p = atomicAdd(&ctrl[0], 1); if (p < ECAP) e0src[p] = src[4*q+1]; }
        if (d.z == 0) { int p = atomicAdd(&ctrl[0], 1); if (p < ECAP) e0src[p] = src[4*q+2]; }
        if (d.w == 0) { int p = atomicAdd(&ctrl[0], 1); if (p < ECAP) e0src[p] = src[4*q+3]; }
    }
}

// ---------------- build S = {srcs of edges into 0} ∪ {0} ----------------
__global__ void k_buildS(int* __restrict__ ctrl, const int* __restrict__ e0src,
                         int* __restrict__ flag, int* __restrict__ S_node) {
    int cnt0 = ctrl[0]; if (cnt0 > ECAP) cnt0 = ECAP;
    int nS = 0;
    for (int i = 0; i <= cnt0; i++) {
        int n = (i < cnt0) ? e0src[i] : 0;   // append node 0 (self-loop of layer 2)
        if (flag[n] < 0) { flag[n] = nS; S_node[nS] = n; nS++; }
    }
    ctrl[2] = nS;
}

// ---------------- pass 2: edges with dst in S -> elist + degS ----------------
__global__ void k_pass2(const int4* __restrict__ dst4, const int* __restrict__ src,
                        const int* __restrict__ flag, int* __restrict__ ctrl,
                        int* __restrict__ elist_src, int* __restrict__ elist_k,
                        int* __restrict__ degS) {
    int i = blockIdx.x * blockDim.x + threadIdx.x;
    int stride = gridDim.x * blockDim.x;
    const int n4 = N_EDGES / 4;
    for (int q = i; q < n4; q += stride) {
        int4 d = dst4[q];
        int dd[4] = {d.x, d.y, d.z, d.w};
        #pragma unroll
        for (int j = 0; j < 4; j++) {
            int k = flag[dd[j]];
            if (k >= 0) {
                atomicAdd(&degS[k], 1);
                int p = atomicAdd(&ctrl[1], 1);
                if (p < ELCAP) { elist_src[p] = src[4*q+j]; elist_k[p] = k; }
            }
        }
    }
}

// ---------------- build T = unique srcs of elist; finalize dinvS ----------------
__global__ void k_buildT(int* __restrict__ ctrl, const int* __restrict__ elist_src,
                         int* __restrict__ flag2, int* __restrict__ elist_m,
                         const int* __restrict__ degS, float* __restrict__ dinvS) {
    int cnt = ctrl[1]; if (cnt > ELCAP) cnt = ELCAP;
    int nT = 0;
    for (int i = 0; i < cnt; i++) {
        int n = elist_src[i];
        int m = flag2[n];
        if (m < 0) { m = nT++; flag2[n] = m; }
        elist_m[i] = m;
    }
    int nS = ctrl[2];
    for (int k = 0; k < nS; k++) dinvS[k] = rsqrtf((float)(degS[k] + 1));
    ctrl[3] = nT;
    ctrl[4] = cnt;
}

// ---------------- pass 3: in-degree of T nodes ----------------
__global__ void k_pass3(const int4* __restrict__ dst4, const int* __restrict__ flag2,
                        int* __restrict__ degT) {
    int i = blockIdx.x * blockDim.x + threadIdx.x;
    int stride = gridDim.x * blockDim.x;
    const int n4 = N_EDGES / 4;
    for (int q = i; q < n4; q += stride) {
        int4 d = dst4[q];
        int m;
        m = flag2[d.x]; if (m >= 0) atomicAdd(&degT[m], 1);
        m = flag2[d.y]; if (m >= 0) atomicAdd(&degT[m], 1);
        m = flag2[d.z]; if (m >= 0) atomicAdd(&degT[m], 1);
        m = flag2[d.w]; if (m >= 0) atomicAdd(&degT[m], 1);
    }
}

// ---------------- fused layer 1 for S nodes: message accum + GEMV + bias + relu ----------------
__global__ void k_fused1(const int* __restrict__ ctrl, const int* __restrict__ S_node,
                         const float* __restrict__ dinvS, const int* __restrict__ elist_src,
                         const int* __restrict__ elist_k, const int* __restrict__ elist_m,
                         const int* __restrict__ degT, const float* __restrict__ x,
                         const float* __restrict__ W1, const float* __restrict__ b1,
                         float* __restrict__ h1) {
    int k = blockIdx.x;
    if (k >= ctrl[2]) return;
    int t = threadIdx.x;             // 128 threads
    int cnt = ctrl[4];
    float dk = dinvS[k];
    int n = S_node[k];
    float sum = x[(size_t)n * IN_DIM + t] * dk * dk;   // self-loop
    for (int i = 0; i < cnt; i++) {
        if (elist_k[i] == k) {
            int u = elist_src[i];
            float norm = rsqrtf((float)(degT[elist_m[i]] + 1)) * dk;
            sum += x[(size_t)u * IN_DIM + t] * norm;
        }
    }
    __shared__ float v[IN_DIM];
    v[t] = sum;
    __syncthreads();
    float h = b1[t];
    #pragma unroll 8
    for (int j = 0; j < IN_DIM; j++) h += v[j] * W1[j * HID_DIM + t];
    h1[k * HID_DIM + t] = fmaxf(h, 0.f);
}

// ---------------- layer 2 for node 0 only ----------------
__global__ void k_layer2(const int* __restrict__ ctrl, const int* __restrict__ e0src,
                         const int* __restrict__ flag, const float* __restrict__ dinvS,
                         const float* __restrict__ h1, const float* __restrict__ W2,
                         const float* __restrict__ b2, float* __restrict__ out) {
    __shared__ float m[HID_DIM];
    int t = threadIdx.x;             // 256 threads
    int cnt0 = ctrl[0]; if (cnt0 > ECAP) cnt0 = ECAP;
    if (t < HID_DIM) {
        int k0 = flag[0];
        float dinv0 = dinvS[k0];
        float s = h1[k0 * HID_DIM + t] * dinv0 * dinv0;      // self-loop
        for (int i = 0; i < cnt0; i++) {
            int n = e0src[i];
            int k = flag[n];
            s += h1[k * HID_DIM + t] * dinvS[k] * dinv0;
        }
        m[t] = s;
    }
    __syncthreads();
    float sum = b2[t];
    #pragma unroll 8
    for (int j = 0; j < HID_DIM; j++) sum += m[j] * W2[j * OUT_DIM + t];
    out[t] = sum;
}

extern "C" void kernel_launch(void* const* d_in, const int* in_sizes, int n_in,
                              void* d_out, int out_size, void* d_ws, size_t ws_size,
                              hipStream_t stream) {
    const float* x  = (const float*)d_in[0];
    const int*   ei = (const int*)d_in[1];           // edge_index flattened [2, E]
    const float* W1 = (const float*)d_in[2];
    const float* b1 = (const float*)d_in[3];
    const float* W2 = (const float*)d_in[4];
    const float* b2 = (const float*)d_in[5];
    float* out = (float*)d_out;

    const int*  src  = ei;                       // edge_index[0]
    const int4* dst4 = (const int4*)(ei + N_EDGES);  // edge_index[1], 16B-aligned (6.4MB offset)

    // workspace carve-up (~1.5 MB)
    char* w = (char*)d_ws;
    int*   flag      = (int*)w;   w += sizeof(int) * N_NODES;
    int*   flag2     = (int*)w;   w += sizeof(int) * N_NODES;
    int*   ctrl      = (int*)w;   w += sizeof(int) * 16;
    int*   e0src     = (int*)w;   w += sizeof(int) * ECAP;
    int*   S_node    = (int*)w;   w += sizeof(int) * SCAP;
    int*   degS      = (int*)w;   w += sizeof(int) * SCAP;
    float* dinvS     = (float*)w; w += sizeof(float) * SCAP;
    int*   elist_src = (int*)w;   w += sizeof(int) * ELCAP;
    int*   elist_k   = (int*)w;   w += sizeof(int) * ELCAP;
    int*   elist_m   = (int*)w;   w += sizeof(int) * ELCAP;
    int*   degT      = (int*)w;   w += sizeof(int) * ELCAP;
    float* h1        = (float*)w; w += sizeof(float) * SCAP * HID_DIM;

    k_init  <<<512, 256, 0, stream>>>(flag, flag2, ctrl, degS, degT);
    k_pass1 <<<1024, 256, 0, stream>>>((const int4*)dst4, src, ctrl, e0src);
    k_buildS<<<1, 1, 0, stream>>>(ctrl, e0src, flag, S_node);
    k_pass2 <<<1024, 256, 0, stream>>>(dst4, src, flag, ctrl, elist_src, elist_k, degS);
    k_buildT<<<1, 1, 0, stream>>>(ctrl, elist_src, flag2, elist_m, degS, dinvS);
    k_pass3 <<<1024, 256, 0, stream>>>(dst4, flag2, degT);
    k_fused1<<<SCAP, IN_DIM, 0, stream>>>(ctrl, S_node, dinvS, elist_src, elist_k, elist_m,
                                          degT, x, W1, b1, h1);
    k_layer2<<<1, OUT_DIM, 0, stream>>>(ctrl, e0src, flag, dinvS, h1, W2, b2, out);
}

// Round 3
// 74.445 us; speedup vs baseline: 2.0110x; 2.0110x over previous
//
#include <hip/hip_runtime.h>

#define N_NODES 100000
#define N_EDGES 1600000
#define IN_DIM  128
#define HID_DIM 128
#define OUT_DIM 256

#define ECAP  1024    // cap on edges into node 0 (expected ~16)
#define SCAP  1056    // cap on S identifiers (>= ECAP+1)
#define ELCAP 8192    // cap on edges into S (expected ~280)

// ctrl: [0]=cnt edges into node0, [1]=elist count, [2]=nS upper bound, [4]=clamped elist count

// ---------------- init workspace ----------------
__global__ void k_init(int* __restrict__ flag, int* __restrict__ flag2,
                       int* __restrict__ ctrl, int* __restrict__ degS,
                       int* __restrict__ degT, int* __restrict__ S_node) {
    int i = blockIdx.x * blockDim.x + threadIdx.x;
    int stride = gridDim.x * blockDim.x;
    int4* f1 = (int4*)flag;
    int4* f2 = (int4*)flag2;
    const int n4 = N_NODES / 4;  // 25000
    int4 m1 = make_int4(-1, -1, -1, -1);
    for (int j = i; j < n4; j += stride) { f1[j] = m1; f2[j] = m1; }
    for (int j = i; j < SCAP; j += stride) { degS[j] = 0; S_node[j] = -1; }
    for (int j = i; j < ELCAP; j += stride) degT[j] = 0;
    if (i < 16) ctrl[i] = 0;
}

// ---------------- pass 1: find edges with dst==0 ----------------
__global__ void k_pass1(const int4* __restrict__ dst4, const int* __restrict__ src,
                        int* __restrict__ ctrl, int* __restrict__ e0src) {
    int i = blockIdx.x * blockDim.x + threadIdx.x;
    int stride = gridDim.x * blockDim.x;
    const int n4 = N_EDGES / 4;
    for (int q = i; q < n4; q += stride) {
        int4 d = dst4[q];
        if (d.x == 0) { int p = atomicAdd(&ctrl[0], 1); if (p < ECAP) e0src[p] = src[4*q+0]; }
        if (d.y == 0) { int p = atomicAdd(&ctrl[0], 1); if (p < ECAP) e0src[p] = src[4*q+1]; }
        if (d.z == 0) { int p = atomicAdd(&ctrl[0], 1); if (p < ECAP) e0src[p] = src[4*q+2]; }
        if (d.w == 0) { int p = atomicAdd(&ctrl[0], 1); if (p < ECAP) e0src[p] = src[4*q+3]; }
    }
}

// ---------------- build S = {srcs of edges into 0} ∪ {0}, parallel CAS-claim ----------------
// identifier k of node n = winning entry index; entry cnt0 is node 0 (layer-2 self-loop)
__global__ void k_buildS(int* __restrict__ ctrl, const int* __restrict__ e0src,
                         int* __restrict__ flag, int* __restrict__ S_node) {
    int cnt0 = ctrl[0]; if (cnt0 > ECAP) cnt0 = ECAP;
    int t = threadIdx.x;
    for (int i = t; i <= cnt0; i += blockDim.x) {
        int n = (i < cnt0) ? e0src[i] : 0;
        atomicCAS(&flag[n], -1, i);
    }
    __syncthreads();
    for (int i = t; i <= cnt0; i += blockDim.x) {
        int n = (i < cnt0) ? e0src[i] : 0;
        if (flag[n] == i) S_node[i] = n;   // winner owns identifier i
    }
    if (t == 0) ctrl[2] = cnt0 + 1;        // upper bound on S identifiers
}

// ---------------- pass 2: edges with dst in S -> elist + degS ----------------
__global__ void k_pass2(const int4* __restrict__ dst4, const int* __restrict__ src,
                        const int* __restrict__ flag, int* __restrict__ ctrl,
                        int* __restrict__ elist_src, int* __restrict__ elist_k,
                        int* __restrict__ degS) {
    int i = blockIdx.x * blockDim.x + threadIdx.x;
    int stride = gridDim.x * blockDim.x;
    const int n4 = N_EDGES / 4;
    for (int q = i; q < n4; q += stride) {
        int4 d = dst4[q];
        int dd[4] = {d.x, d.y, d.z, d.w};
        #pragma unroll
        for (int j = 0; j < 4; j++) {
            int k = flag[dd[j]];
            if (k >= 0) {
                atomicAdd(&degS[k], 1);
                int p = atomicAdd(&ctrl[1], 1);
                if (p < ELCAP) { elist_src[p] = src[4*q+j]; elist_k[p] = k; }
            }
        }
    }
}

// ---------------- build T (parallel CAS-claim by elist entry index) + dinvS ----------------
__global__ void k_buildT(int* __restrict__ ctrl, const int* __restrict__ elist_src,
                         int* __restrict__ flag2, int* __restrict__ elist_m,
                         const int* __restrict__ degS, float* __restrict__ dinvS,
                         const int* __restrict__ S_node) {
    int cnt = ctrl[1]; if (cnt > ELCAP) cnt = ELCAP;
    int t = threadIdx.x;
    for (int i = t; i < cnt; i += blockDim.x)
        atomicCAS(&flag2[elist_src[i]], -1, i);
    __syncthreads();
    for (int i = t; i < cnt; i += blockDim.x)
        elist_m[i] = flag2[elist_src[i]];
    int nS = ctrl[2];
    for (int k = t; k < nS; k += blockDim.x)
        if (S_node[k] >= 0) dinvS[k] = rsqrtf((float)(degS[k] + 1));
    if (t == 0) ctrl[4] = cnt;
}

// ---------------- pass 3: in-degree of T nodes (identified by winning elist entry) ----------------
__global__ void k_pass3(const int4* __restrict__ dst4, const int* __restrict__ flag2,
                        int* __restrict__ degT) {
    int i = blockIdx.x * blockDim.x + threadIdx.x;
    int stride = gridDim.x * blockDim.x;
    const int n4 = N_EDGES / 4;
    for (int q = i; q < n4; q += stride) {
        int4 d = dst4[q];
        int m;
        m = flag2[d.x]; if (m >= 0) atomicAdd(&degT[m], 1);
        m = flag2[d.y]; if (m >= 0) atomicAdd(&degT[m], 1);
        m = flag2[d.z]; if (m >= 0) atomicAdd(&degT[m], 1);
        m = flag2[d.w]; if (m >= 0) atomicAdd(&degT[m], 1);
    }
}

// ---------------- fused layer 1 for S nodes: message accum + GEMV + bias + relu ----------------
__global__ void k_fused1(const int* __restrict__ ctrl, const int* __restrict__ S_node,
                         const float* __restrict__ dinvS, const int* __restrict__ elist_src,
                         const int* __restrict__ elist_k, const int* __restrict__ elist_m,
                         const int* __restrict__ degT, const float* __restrict__ x,
                         const float* __restrict__ W1, const float* __restrict__ b1,
                         float* __restrict__ h1) {
    int k = blockIdx.x;
    int n = S_node[k];
    if (n < 0) return;                 // identifier not claimed
    int t = threadIdx.x;               // 128 threads
    int cnt = ctrl[4];
    float dk = dinvS[k];
    float sum = x[(size_t)n * IN_DIM + t] * dk * dk;   // self-loop
    for (int i = 0; i < cnt; i++) {
        if (elist_k[i] == k) {
            int u = elist_src[i];
            float norm = rsqrtf((float)(degT[elist_m[i]] + 1)) * dk;
            sum += x[(size_t)u * IN_DIM + t] * norm;
        }
    }
    __shared__ float v[IN_DIM];
    v[t] = sum;
    __syncthreads();
    float h = b1[t];
    #pragma unroll 8
    for (int j = 0; j < IN_DIM; j++) h += v[j] * W1[j * HID_DIM + t];
    h1[k * HID_DIM + t] = fmaxf(h, 0.f);
}

// ---------------- layer 2 for node 0 only ----------------
__global__ void k_layer2(const int* __restrict__ ctrl, const int* __restrict__ e0src,
                         const int* __restrict__ flag, const float* __restrict__ dinvS,
                         const float* __restrict__ h1, const float* __restrict__ W2,
                         const float* __restrict__ b2, float* __restrict__ out) {
    __shared__ float m[HID_DIM];
    int t = threadIdx.x;               // 256 threads
    int cnt0 = ctrl[0]; if (cnt0 > ECAP) cnt0 = ECAP;
    if (t < HID_DIM) {
        int k0 = flag[0];
        float dinv0 = dinvS[k0];
        float s = h1[k0 * HID_DIM + t] * dinv0 * dinv0;      // self-loop
        for (int i = 0; i < cnt0; i++) {
            int n = e0src[i];
            int k = flag[n];
            s += h1[k * HID_DIM + t] * dinvS[k] * dinv0;
        }
        m[t] = s;
    }
    __syncthreads();
    float sum = b2[t];
    #pragma unroll 8
    for (int j = 0; j < HID_DIM; j++) sum += m[j] * W2[j * OUT_DIM + t];
    out[t] = sum;
}

extern "C" void kernel_launch(void* const* d_in, const int* in_sizes, int n_in,
                              void* d_out, int out_size, void* d_ws, size_t ws_size,
                              hipStream_t stream) {
    const float* x  = (const float*)d_in[0];
    const int*   ei = (const int*)d_in[1];           // edge_index flattened [2, E]
    const float* W1 = (const float*)d_in[2];
    const float* b1 = (const float*)d_in[3];
    const float* W2 = (const float*)d_in[4];
    const float* b2 = (const float*)d_in[5];
    float* out = (float*)d_out;

    const int*  src  = ei;                           // edge_index[0]
    const int4* dst4 = (const int4*)(ei + N_EDGES);  // edge_index[1], 16B-aligned

    // workspace carve-up (~1.5 MB)
    char* w = (char*)d_ws;
    int*   flag      = (int*)w;   w += sizeof(int) * N_NODES;
    int*   flag2     = (int*)w;   w += sizeof(int) * N_NODES;
    int*   ctrl      = (int*)w;   w += sizeof(int) * 16;
    int*   e0src     = (int*)w;   w += sizeof(int) * ECAP;
    int*   S_node    = (int*)w;   w += sizeof(int) * SCAP;
    int*   degS      = (int*)w;   w += sizeof(int) * SCAP;
    float* dinvS     = (float*)w; w += sizeof(float) * SCAP;
    int*   elist_src = (int*)w;   w += sizeof(int) * ELCAP;
    int*   elist_k   = (int*)w;   w += sizeof(int) * ELCAP;
    int*   elist_m   = (int*)w;   w += sizeof(int) * ELCAP;
    int*   degT      = (int*)w;   w += sizeof(int) * ELCAP;
    float* h1        = (float*)w; w += sizeof(float) * SCAP * HID_DIM;

    k_init  <<<512, 256, 0, stream>>>(flag, flag2, ctrl, degS, degT, S_node);
    k_pass1 <<<1024, 256, 0, stream>>>(dst4, src, ctrl, e0src);
    k_buildS<<<1, 1024, 0, stream>>>(ctrl, e0src, flag, S_node);
    k_pass2 <<<1024, 256, 0, stream>>>(dst4, src, flag, ctrl, elist_src, elist_k, degS);
    k_buildT<<<1, 1024, 0, stream>>>(ctrl, elist_src, flag2, elist_m, degS, dinvS, S_node);
    k_pass3 <<<1024, 256, 0, stream>>>(dst4, flag2, degT);
    k_fused1<<<SCAP, IN_DIM, 0, stream>>>(ctrl, S_node, dinvS, elist_src, elist_k, elist_m,
                                          degT, x, W1, b1, h1);
    k_layer2<<<1, OUT_DIM, 0, stream>>>(ctrl, e0src, flag, dinvS, h1, W2, b2, out);
}

// Round 4
// 49.928 us; speedup vs baseline: 2.9985x; 1.4910x over previous
//
#include <hip/hip_runtime.h>

#define N_NODES 100000
#define N_EDGES 1600000
#define IN_DIM  128
#define HID_DIM 128
#define OUT_DIM 256

#define ECAP  1024    // cap on edges into node 0 (expected ~16)
#define SCAP  1056    // cap on S identifiers (>= ECAP+1)
#define ELCAP 8192    // cap on edges into S (expected ~280)

// ctrl: [0]=cnt edges into node0, [1]=elist count, [2]=nS upper bound, [4]=clamped elist count

// ---------------- init workspace ----------------
__global__ void k_init(int* __restrict__ flag, int* __restrict__ flag2,
                       int* __restrict__ ctrl, int* __restrict__ degS,
                       int* __restrict__ degT, int* __restrict__ S_node,
                       float* __restrict__ acc) {
    int i = blockIdx.x * blockDim.x + threadIdx.x;
    int stride = gridDim.x * blockDim.x;
    int4* f1 = (int4*)flag;
    int4* f2 = (int4*)flag2;
    const int n4 = N_NODES / 4;  // 25000
    int4 m1 = make_int4(-1, -1, -1, -1);
    for (int j = i; j < n4; j += stride) { f1[j] = m1; f2[j] = m1; }
    for (int j = i; j < SCAP; j += stride) { degS[j] = 0; S_node[j] = -1; }
    for (int j = i; j < ELCAP; j += stride) degT[j] = 0;
    float4* a4 = (float4*)acc;
    const int na4 = SCAP * IN_DIM / 4;
    float4 z = make_float4(0.f, 0.f, 0.f, 0.f);
    for (int j = i; j < na4; j += stride) a4[j] = z;
    if (i < 16) ctrl[i] = 0;
}

// ---------------- pass 1: find edges with dst==0 ----------------
__global__ void k_pass1(const int4* __restrict__ dst4, const int* __restrict__ src,
                        int* __restrict__ ctrl, int* __restrict__ e0src) {
    int i = blockIdx.x * blockDim.x + threadIdx.x;
    int stride = gridDim.x * blockDim.x;
    const int n4 = N_EDGES / 4;
    for (int q = i; q < n4; q += stride) {
        int4 d = dst4[q];
        if (d.x == 0) { int p = atomicAdd(&ctrl[0], 1); if (p < ECAP) e0src[p] = src[4*q+0]; }
        if (d.y == 0) { int p = atomicAdd(&ctrl[0], 1); if (p < ECAP) e0src[p] = src[4*q+1]; }
        if (d.z == 0) { int p = atomicAdd(&ctrl[0], 1); if (p < ECAP) e0src[p] = src[4*q+2]; }
        if (d.w == 0) { int p = atomicAdd(&ctrl[0], 1); if (p < ECAP) e0src[p] = src[4*q+3]; }
    }
}

// ---------------- build S = {srcs of edges into 0} ∪ {0}, parallel CAS-claim ----------------
__global__ void k_buildS(int* __restrict__ ctrl, const int* __restrict__ e0src,
                         int* __restrict__ flag, int* __restrict__ S_node) {
    int cnt0 = ctrl[0]; if (cnt0 > ECAP) cnt0 = ECAP;
    int t = threadIdx.x;
    for (int i = t; i <= cnt0; i += blockDim.x) {
        int n = (i < cnt0) ? e0src[i] : 0;
        atomicCAS(&flag[n], -1, i);
    }
    __syncthreads();
    for (int i = t; i <= cnt0; i += blockDim.x) {
        int n = (i < cnt0) ? e0src[i] : 0;
        if (flag[n] == i) S_node[i] = n;   // winner owns identifier i
    }
    if (t == 0) ctrl[2] = cnt0 + 1;
}

// ---------------- pass 2: edges with dst in S -> elist + degS ----------------
__global__ void k_pass2(const int4* __restrict__ dst4, const int* __restrict__ src,
                        const int* __restrict__ flag, int* __restrict__ ctrl,
                        int* __restrict__ elist_src, int* __restrict__ elist_k,
                        int* __restrict__ degS) {
    int i = blockIdx.x * blockDim.x + threadIdx.x;
    int stride = gridDim.x * blockDim.x;
    const int n4 = N_EDGES / 4;
    for (int q = i; q < n4; q += stride) {
        int4 d = dst4[q];
        int dd[4] = {d.x, d.y, d.z, d.w};
        #pragma unroll
        for (int j = 0; j < 4; j++) {
            int k = flag[dd[j]];
            if (k >= 0) {
                atomicAdd(&degS[k], 1);
                int p = atomicAdd(&ctrl[1], 1);
                if (p < ELCAP) { elist_src[p] = src[4*q+j]; elist_k[p] = k; }
            }
        }
    }
}

// ---------------- build T (parallel CAS-claim by elist entry index) + dinvS ----------------
__global__ void k_buildT(int* __restrict__ ctrl, const int* __restrict__ elist_src,
                         int* __restrict__ flag2, int* __restrict__ elist_m,
                         const int* __restrict__ degS, float* __restrict__ dinvS,
                         const int* __restrict__ S_node) {
    int cnt = ctrl[1]; if (cnt > ELCAP) cnt = ELCAP;
    int t = threadIdx.x;
    for (int i = t; i < cnt; i += blockDim.x)
        atomicCAS(&flag2[elist_src[i]], -1, i);
    __syncthreads();
    for (int i = t; i < cnt; i += blockDim.x)
        elist_m[i] = flag2[elist_src[i]];
    int nS = ctrl[2];
    for (int k = t; k < nS; k += blockDim.x)
        if (S_node[k] >= 0) dinvS[k] = rsqrtf((float)(degS[k] + 1));
    if (t == 0) ctrl[4] = cnt;
}

// ---------------- pass 3: in-degree of T nodes ----------------
__global__ void k_pass3(const int4* __restrict__ dst4, const int* __restrict__ flag2,
                        int* __restrict__ degT) {
    int i = blockIdx.x * blockDim.x + threadIdx.x;
    int stride = gridDim.x * blockDim.x;
    const int n4 = N_EDGES / 4;
    for (int q = i; q < n4; q += stride) {
        int4 d = dst4[q];
        int m;
        m = flag2[d.x]; if (m >= 0) atomicAdd(&degT[m], 1);
        m = flag2[d.y]; if (m >= 0) atomicAdd(&degT[m], 1);
        m = flag2[d.z]; if (m >= 0) atomicAdd(&degT[m], 1);
        m = flag2[d.w]; if (m >= 0) atomicAdd(&degT[m], 1);
    }
}

// ---------------- edge-parallel accumulate: acc[k] += x[src]*norm ----------------
__global__ void k_accum(const int* __restrict__ ctrl, const int* __restrict__ elist_src,
                        const int* __restrict__ elist_k, const int* __restrict__ elist_m,
                        const int* __restrict__ degT, const float* __restrict__ dinvS,
                        const float* __restrict__ x, float* __restrict__ acc) {
    int cnt = ctrl[4];
    int t = threadIdx.x;              // 128 threads = one dim each
    for (int i = blockIdx.x; i < cnt; i += gridDim.x) {
        int k = elist_k[i];
        int u = elist_src[i];
        float norm = rsqrtf((float)(degT[elist_m[i]] + 1)) * dinvS[k];
        atomicAdd(&acc[k * IN_DIM + t], x[(size_t)u * IN_DIM + t] * norm);
    }
}

// ---------------- layer 1 per S-node: self-loop + GEMV + bias + relu ----------------
__global__ void k_layer1(const int* __restrict__ S_node, const float* __restrict__ dinvS,
                         const float* __restrict__ x, const float* __restrict__ acc,
                         const float* __restrict__ W1, const float* __restrict__ b1,
                         float* __restrict__ h1) {
    int k = blockIdx.x;
    int n = S_node[k];
    if (n < 0) return;                 // identifier not claimed
    int t = threadIdx.x;               // 128 threads
    float dk = dinvS[k];
    __shared__ float v[IN_DIM];
    v[t] = acc[k * IN_DIM + t] + x[(size_t)n * IN_DIM + t] * dk * dk;
    __syncthreads();
    float h = b1[t];
    #pragma unroll 8
    for (int j = 0; j < IN_DIM; j++) h += v[j] * W1[j * HID_DIM + t];
    h1[k * HID_DIM + t] = fmaxf(h, 0.f);
}

// ---------------- layer 2 for node 0 only ----------------
__global__ void k_layer2(const int* __restrict__ ctrl, const int* __restrict__ e0src,
                         const int* __restrict__ flag, const float* __restrict__ dinvS,
                         const float* __restrict__ h1, const float* __restrict__ W2,
                         const float* __restrict__ b2, float* __restrict__ out) {
    __shared__ float m[HID_DIM];
    int t = threadIdx.x;               // 256 threads
    int cnt0 = ctrl[0]; if (cnt0 > ECAP) cnt0 = ECAP;
    if (t < HID_DIM) {
        int k0 = flag[0];
        float dinv0 = dinvS[k0];
        float s = h1[k0 * HID_DIM + t] * dinv0 * dinv0;      // self-loop
        for (int i = 0; i < cnt0; i++) {
            int n = e0src[i];
            int k = flag[n];
            s += h1[k * HID_DIM + t] * dinvS[k] * dinv0;
        }
        m[t] = s;
    }
    __syncthreads();
    float sum = b2[t];
    #pragma unroll 8
    for (int j = 0; j < HID_DIM; j++) sum += m[j] * W2[j * OUT_DIM + t];
    out[t] = sum;
}

extern "C" void kernel_launch(void* const* d_in, const int* in_sizes, int n_in,
                              void* d_out, int out_size, void* d_ws, size_t ws_size,
                              hipStream_t stream) {
    const float* x  = (const float*)d_in[0];
    const int*   ei = (const int*)d_in[1];           // edge_index flattened [2, E]
    const float* W1 = (const float*)d_in[2];
    const float* b1 = (const float*)d_in[3];
    const float* W2 = (const float*)d_in[4];
    const float* b2 = (const float*)d_in[5];
    float* out = (float*)d_out;

    const int*  src  = ei;                           // edge_index[0]
    const int4* dst4 = (const int4*)(ei + N_EDGES);  // edge_index[1], 16B-aligned

    // workspace carve-up (~2.1 MB)
    char* w = (char*)d_ws;
    int*   flag      = (int*)w;   w += sizeof(int) * N_NODES;
    int*   flag2     = (int*)w;   w += sizeof(int) * N_NODES;
    int*   ctrl      = (int*)w;   w += sizeof(int) * 16;
    int*   e0src     = (int*)w;   w += sizeof(int) * ECAP;
    int*   S_node    = (int*)w;   w += sizeof(int) * SCAP;
    int*   degS      = (int*)w;   w += sizeof(int) * SCAP;
    float* dinvS     = (float*)w; w += sizeof(float) * SCAP;
    int*   elist_src = (int*)w;   w += sizeof(int) * ELCAP;
    int*   elist_k   = (int*)w;   w += sizeof(int) * ELCAP;
    int*   elist_m   = (int*)w;   w += sizeof(int) * ELCAP;
    int*   degT      = (int*)w;   w += sizeof(int) * ELCAP;
    float* acc       = (float*)w; w += sizeof(float) * SCAP * IN_DIM;
    float* h1        = (float*)w; w += sizeof(float) * SCAP * HID_DIM;

    k_init  <<<512, 256, 0, stream>>>(flag, flag2, ctrl, degS, degT, S_node, acc);
    k_pass1 <<<1024, 256, 0, stream>>>(dst4, src, ctrl, e0src);
    k_buildS<<<1, 1024, 0, stream>>>(ctrl, e0src, flag, S_node);
    k_pass2 <<<1024, 256, 0, stream>>>(dst4, src, flag, ctrl, elist_src, elist_k, degS);
    k_buildT<<<1, 1024, 0, stream>>>(ctrl, elist_src, flag2, elist_m, degS, dinvS, S_node);
    k_pass3 <<<1024, 256, 0, stream>>>(dst4, flag2, degT);
    k_accum <<<512, IN_DIM, 0, stream>>>(ctrl, elist_src, elist_k, elist_m, degT, dinvS, x, acc);
    k_layer1<<<SCAP, IN_DIM, 0, stream>>>(S_node, dinvS, x, acc, W1, b1, h1);
    k_layer2<<<1, OUT_DIM, 0, stream>>>(ctrl, e0src, flag, dinvS, h1, W2, b2, out);
}